// Round 17
// baseline (260.559 us; speedup 1.0000x reference)
//
#include <hip/hip_runtime.h>
#include <hip/hip_fp16.h>

// ---------------------------------------------------------------------------
// DoubleAttention (A^2-Net) on MI355X.  B=16, C=512, N=4096, cm=cn=128.
// Round 16: R16 base + (1) gd-granule-tiled A/Bm (coalesced k_gd), plain
// stores + gdred (no atomics), (2) XCD co-location swizzle for abv's 3 mg
// blocks, (3) 2-phase double-buffer in abv and gd K-loops.
//   k_prep     : W->fp16 (perm'd contraction axis)
//   k_gemm_abv : 1536 blocks (xcd-swizzled), 128m x 128n, K=512, dbuf.
//                x read fp32 directly via glds16 (linear dest, pre-swizzled
//                source); fragment cvt at read. Outputs: A,Bm in gd-tiled
//                granule layout [b][ks][st][kg][m][8]; VmT[b][n][k'].
//   k_gd       : per (ks,b): contiguous glds16 slab staging, dbuf, 8 steps;
//                plain f32x4 partial stores gdP[b][ks][k][m].
//   k_gdred    : gdT[b][k][m] = sum_ks gdP
//   k_gw       : GW[b] = WR @ gd[b]   (out = (WR*gd)*Vm)
//   k_out      : out = GW @ Vm + bR
// Contraction-axis fp16 tensors perm'd within 32:
//   p(k)=((k&15)>>2)*8+((k>>4)&1)*4+(k&3)  (16B chunks == MFMA fragments).
// ---------------------------------------------------------------------------

typedef _Float16 half8 __attribute__((ext_vector_type(8)));
typedef float f32x4 __attribute__((ext_vector_type(4)));

__device__ __forceinline__ unsigned short f2h(float v) {
  return __builtin_bit_cast(unsigned short, (_Float16)v);
}
__device__ __forceinline__ unsigned pk2(float a, float b) {
  return (unsigned)f2h(a) | ((unsigned)f2h(b) << 16);
}
__device__ __forceinline__ f32x4 mfma16(half8 a, half8 b, f32x4 c) {
  return __builtin_amdgcn_mfma_f32_16x16x32_f16(a, b, c, 0, 0, 0);
}
__device__ __forceinline__ int perm32(int v) {  // v in [0,32)
  return (((v & 15) >> 2) << 3) | (((v >> 4) & 1) << 2) | (v & 3);
}
__device__ __forceinline__ void glds16(const void* g, void* l) {
  __builtin_amdgcn_global_load_lds(
      (const __attribute__((address_space(1))) unsigned int*)g,
      (__attribute__((address_space(3))) unsigned int*)l, 16, 0, 0);
}
// fragment read from a 128-row fp16 granule tile
__device__ __forceinline__ half8 ld_frag(const unsigned short* lds, int row) {
  int kg = (threadIdx.x & 63) >> 4;
  uint4 u = *(const uint4*)&lds[(kg * 128 + row) * 8];
  return __builtin_bit_cast(half8, u);
}
// B-fragment from swizzled fp32 x tile [32 c][128 n] (R16-verified).
__device__ __forceinline__ half8 ld_frag_x128(const float* lds, int n) {
  const int lane = threadIdx.x & 63;
  const int kg = lane >> 4;
  const int q = n >> 2, r = n & 3;
  float v[8];
#pragma unroll
  for (int j = 0; j < 4; ++j) {
    int c0 = 4 * kg + j, c1 = c0 + 16;
    v[j]     = lds[c0 * 128 + ((q ^ c0) & 31) * 4 + r];
    v[4 + j] = lds[c1 * 128 + ((q ^ c1) & 31) * 4 + r];
  }
  uint4 u;
  u.x = pk2(v[0], v[1]); u.y = pk2(v[2], v[3]);
  u.z = pk2(v[4], v[5]); u.w = pk2(v[6], v[7]);
  return __builtin_bit_cast(half8, u);
}

// 256-thread stager: [128 rows][32 k(perm'd)] fp16 tile via glds16.
__device__ __forceinline__ void stage_glds256(unsigned short* lds,
                                              const unsigned short* g,
                                              int gs, int k0) {
  const int lane = threadIdx.x & 63;
  const int w = threadIdx.x >> 6;
#pragma unroll
  for (int p = 0; p < 2; ++p) {
    int g0 = (w + p * 4) * 64;
    int gi = g0 + lane;
    int row = gi & 127, kg = gi >> 7;
    glds16(g + (size_t)row * gs + k0 + kg * 8, lds + g0 * 8);
  }
}

// contiguous slab stager: 512 x 16B granules in storage order.
__device__ __forceinline__ void stage_slab(unsigned short* lds,
                                           const unsigned short* slab) {
  const int lane = threadIdx.x & 63;
  const int w = threadIdx.x >> 6;
#pragma unroll
  for (int p = 0; p < 2; ++p) {
    int g0 = (w + p * 4) * 64;
    glds16(slab + (size_t)(g0 + lane) * 8, lds + g0 * 8);
  }
}

// ---------------------------------------------------------------------------
__global__ __launch_bounds__(256) void k_prep(
    const float* __restrict__ WA, const float* __restrict__ WB,
    const float* __restrict__ WV, const float* __restrict__ WR,
    unsigned short* __restrict__ Wh, unsigned short* __restrict__ WRh) {
  int idx = blockIdx.x * 256 + threadIdx.x;  // 0..262143
  if (idx < 196608) {
    int mg = idx >> 16, r = idx & 65535;
    const float* src = (mg == 0) ? WA : ((mg == 1) ? WB : WV);
    Wh[(idx & ~31) | perm32(idx & 31)] = f2h(src[r]);
  } else {
    int r = idx - 196608;
    WRh[(r & ~31) | perm32(r & 31)] = f2h(WR[r]);
  }
}

// ---------------------------------------------------------------------------
// ABV GEMM + fused channel-softmax; 1536 blocks 1D, XCD-swizzled so the
// 3 mg blocks of one (nt,b) share an XCD (L2 reuse of the x tile).
__global__ __launch_bounds__(256) void k_gemm_abv(
    const float* __restrict__ x, const unsigned short* __restrict__ Wh,
    const float* __restrict__ bA, const float* __restrict__ bB,
    const float* __restrict__ bV,
    unsigned short* __restrict__ Ag, unsigned short* __restrict__ Bg,
    unsigned short* __restrict__ VmTout) {
  const int bid = blockIdx.x;
  const int xcd = bid & 7, jj0 = bid >> 3;     // jj0 0..191
  const int mg = jj0 % 3, tl = jj0 / 3;        // tl 0..63
  const int triple = xcd * 64 + tl;            // 0..511
  const int nt = triple & 31, b = triple >> 5;

  const int tid = threadIdx.x, lane = tid & 63;
  const int w = tid >> 6, wr = w >> 1, wc = w & 1;
  const int kg = lane >> 4, lidx = lane & 15;

  __shared__ unsigned short sW[2][4096];           // 16 KB fp16 W dbuf
  __shared__ __align__(16) float sX[2][4096];      // 32 KB fp32 x dbuf
  __shared__ float colmax[2][128], colsum[2][128], sBias[128];

  const float* bias = (mg == 0) ? bA : ((mg == 1) ? bB : bV);
  if (tid < 128) sBias[tid] = bias[tid];

  const unsigned short* Wg = Wh + (size_t)mg * 128 * 512;
  const float* xsrc = x + (size_t)b * 512 * 4096 + nt * 128;

  // stage [32 c][128 n] fp32 tile: 1024 linear granules, pre-swizzled source.
#define XSTAGE32(BUF, K0) do { \
  _Pragma("unroll") for (int p_ = 0; p_ < 4; ++p_) { \
    int g0_ = (tid >> 6) * 64 + p_ * 256;   /* wave-uniform slot base */ \
    int s_ = g0_ + lane; \
    int c_ = s_ >> 5, qp_ = s_ & 31; \
    glds16(xsrc + (size_t)((K0) + c_) * 4096 + ((qp_ ^ c_) << 2), \
           sX[BUF] + (size_t)g0_ * 4); \
  } } while (0)

  f32x4 acc[4][4];
#pragma unroll
  for (int mf = 0; mf < 4; ++mf)
#pragma unroll
    for (int nf = 0; nf < 4; ++nf) acc[mf][nf] = (f32x4){0.f, 0.f, 0.f, 0.f};

  // prologue: stage step 0
  stage_glds256(sW[0], Wg, 512, 0);
  XSTAGE32(0, 0);
  __syncthreads();

  for (int ks = 0; ks < 16; ++ks) {
    const int cur = ks & 1, nxt = cur ^ 1;
    if (ks < 15) {                       // prefetch next BEFORE compute
      stage_glds256(sW[nxt], Wg, 512, (ks + 1) * 32);
      XSTAGE32(nxt, (ks + 1) * 32);
    }
    half8 af[4];
#pragma unroll
    for (int mf = 0; mf < 4; ++mf) af[mf] = ld_frag(sW[cur], wr * 64 + mf * 16 + lidx);
#pragma unroll
    for (int nf = 0; nf < 4; ++nf) {
      half8 bf = ld_frag_x128(sX[cur], wc * 64 + nf * 16 + lidx);
#pragma unroll
      for (int mf = 0; mf < 4; ++mf) acc[mf][nf] = mfma16(af[mf], bf, acc[mf][nf]);
    }
    __syncthreads();                     // drains prefetch (hidden by compute)
  }

  // bias (rows m = wr*64 + mf*16 + kg*4 + i)
#pragma unroll
  for (int mf = 0; mf < 4; ++mf)
#pragma unroll
    for (int i = 0; i < 4; ++i) {
      float bb = sBias[wr * 64 + mf * 16 + kg * 4 + i];
#pragma unroll
      for (int nf = 0; nf < 4; ++nf) acc[mf][nf][i] += bb;
    }

  // gd-granule-tiled destination index per nf:
  //   n = nt*128 + wc*64 + nf*16 + lidx; ks2 = nt>>1; n2 = n&255;
  //   st = n2>>5; j = n2&31; kg2 = (j&15)>>2; h = ((j>>4)&1)*4 + (j&3)
  //   addr = ((b*16+ks2)*32768) + st*4096 + kg2*1024 + m*8 + h
  const int ks2 = nt >> 1;
  size_t tbase[4]; // per-nf base (without m term)
#pragma unroll
  for (int nf = 0; nf < 4; ++nf) {
    int n2 = (nt & 1) * 128 + wc * 64 + nf * 16 + lidx;
    int st = n2 >> 5, j2 = n2 & 31;
    tbase[nf] = ((size_t)(b * 16 + ks2)) * 32768 + st * 4096 +
                ((j2 & 15) >> 2) * 1024 + ((j2 >> 4) & 1) * 4 + (j2 & 3);
  }

  if (mg == 0) {  // A -> tiled layout
#pragma unroll
    for (int mf = 0; mf < 4; ++mf)
#pragma unroll
      for (int nf = 0; nf < 4; ++nf)
#pragma unroll
        for (int i = 0; i < 4; ++i) {
          int m_ = wr * 64 + mf * 16 + kg * 4 + i;
          Ag[tbase[nf] + (size_t)m_ * 8] = f2h(acc[mf][nf][i]);
        }
    return;
  }

  // softmax over 128 m-rows per column n
  float cmax[4], csum[4];
#pragma unroll
  for (int nf = 0; nf < 4; ++nf) {
    float m = -1e30f;
#pragma unroll
    for (int mf = 0; mf < 4; ++mf)
#pragma unroll
      for (int i = 0; i < 4; ++i) m = fmaxf(m, acc[mf][nf][i]);
    m = fmaxf(m, __shfl_xor(m, 16));
    m = fmaxf(m, __shfl_xor(m, 32));
    cmax[nf] = m;
  }
  if (kg == 0) {
#pragma unroll
    for (int nf = 0; nf < 4; ++nf) colmax[wr][wc * 64 + nf * 16 + lidx] = cmax[nf];
  }
  __syncthreads();
#pragma unroll
  for (int nf = 0; nf < 4; ++nf)
    cmax[nf] = fmaxf(cmax[nf], colmax[wr ^ 1][wc * 64 + nf * 16 + lidx]);
#pragma unroll
  for (int nf = 0; nf < 4; ++nf) {
    float s = 0.f;
#pragma unroll
    for (int mf = 0; mf < 4; ++mf)
#pragma unroll
      for (int i = 0; i < 4; ++i) {
        float e = __expf(acc[mf][nf][i] - cmax[nf]);
        acc[mf][nf][i] = e;
        s += e;
      }
    s += __shfl_xor(s, 16);
    s += __shfl_xor(s, 32);
    csum[nf] = s;
  }
  if (kg == 0) {
#pragma unroll
    for (int nf = 0; nf < 4; ++nf) colsum[wr][wc * 64 + nf * 16 + lidx] = csum[nf];
  }
  __syncthreads();
  float inv_s[4];
#pragma unroll
  for (int nf = 0; nf < 4; ++nf)
    inv_s[nf] = 1.f / (csum[nf] + colsum[wr ^ 1][wc * 64 + nf * 16 + lidx]);

  if (mg == 1) {  // Bm -> tiled layout
#pragma unroll
    for (int mf = 0; mf < 4; ++mf)
#pragma unroll
      for (int nf = 0; nf < 4; ++nf)
#pragma unroll
        for (int i = 0; i < 4; ++i) {
          int m_ = wr * 64 + mf * 16 + kg * 4 + i;
          Bg[tbase[nf] + (size_t)m_ * 8] = f2h(acc[mf][nf][i] * inv_s[nf]);
        }
  } else {        // VmT[b][n][k'] (k=cn channel, perm'd; aligned-4 packs)
    const size_t vofs = (size_t)b * 4096 * 128;
#pragma unroll
    for (int mf = 0; mf < 4; ++mf)
#pragma unroll
      for (int nf = 0; nf < 4; ++nf) {
        int m0 = wr * 64 + mf * 16 + kg * 4;
        int mp = (m0 & ~31) + perm32(m0 & 31);
        int n_ = nt * 128 + wc * 64 + nf * 16 + lidx;
        ushort4 pk;
        pk.x = f2h(acc[mf][nf][0] * inv_s[nf]);
        pk.y = f2h(acc[mf][nf][1] * inv_s[nf]);
        pk.z = f2h(acc[mf][nf][2] * inv_s[nf]);
        pk.w = f2h(acc[mf][nf][3] * inv_s[nf]);
        *(ushort4*)&VmTout[vofs + (size_t)n_ * 128 + mp] = pk;
      }
  }
#undef XSTAGE32
}

// ---------------------------------------------------------------------------
// gdP[b][ks][k][m] = A_slab(m,n) . Bm_slab(k,n) over n=256; grid (16 ks, 16 b)
// Slabs are stored in granule order -> fully coalesced glds16 staging.
__global__ __launch_bounds__(256) void k_gd(
    const unsigned short* __restrict__ Ag, const unsigned short* __restrict__ Bg,
    float* __restrict__ gdP) {
  const int ks = blockIdx.x, b = blockIdx.y;
  const int tid = threadIdx.x, lane = tid & 63;
  const int w = tid >> 6, wr = w >> 1, wc = w & 1;
  const int kg = lane >> 4, lidx = lane & 15;
  __shared__ unsigned short sA[2][4096], sB[2][4096];
  const unsigned short* As = Ag + ((size_t)(b * 16 + ks)) * 32768;
  const unsigned short* Bs = Bg + ((size_t)(b * 16 + ks)) * 32768;

  f32x4 acc[4][4];
#pragma unroll
  for (int mf = 0; mf < 4; ++mf)
#pragma unroll
    for (int nf = 0; nf < 4; ++nf) acc[mf][nf] = (f32x4){0.f, 0.f, 0.f, 0.f};

  stage_slab(sA[0], As);
  stage_slab(sB[0], Bs);
  __syncthreads();
  for (int st = 0; st < 8; ++st) {
    const int cur = st & 1, nxt = cur ^ 1;
    if (st < 7) {
      stage_slab(sA[nxt], As + (st + 1) * 4096);
      stage_slab(sB[nxt], Bs + (st + 1) * 4096);
    }
    half8 af[4];
#pragma unroll
    for (int mf = 0; mf < 4; ++mf) af[mf] = ld_frag(sA[cur], wr * 64 + mf * 16 + lidx);
#pragma unroll
    for (int nf = 0; nf < 4; ++nf) {
      half8 bf = ld_frag(sB[cur], wc * 64 + nf * 16 + lidx);
#pragma unroll
      for (int mf = 0; mf < 4; ++mf) acc[mf][nf] = mfma16(af[mf], bf, acc[mf][nf]);
    }
    __syncthreads();
  }
  float* gp = gdP + ((size_t)(b * 16 + ks)) * 16384;  // [k][m]
#pragma unroll
  for (int mf = 0; mf < 4; ++mf)
#pragma unroll
    for (int nf = 0; nf < 4; ++nf) {
      int m0 = wr * 64 + mf * 16 + kg * 4;
      int k2 = wc * 64 + nf * 16 + lidx;
      *(f32x4*)&gp[(size_t)k2 * 128 + m0] = acc[mf][nf];
    }
}

// ---------------------------------------------------------------------------
// gdT[b][k][m] = sum_ks(16) gdP[b][ks][k][m]; one float per thread.
__global__ __launch_bounds__(256) void k_gdred(
    const float* __restrict__ gdP, float* __restrict__ gdT) {
  int gid = blockIdx.x * 256 + threadIdx.x;  // 0..262143
  int b = gid >> 14, km = gid & 16383;
  const float* src = gdP + (size_t)b * 16 * 16384 + km;
  float s = 0.f;
#pragma unroll
  for (int ks = 0; ks < 16; ++ks) s += src[(size_t)ks * 16384];
  gdT[gid] = s;
}

// ---------------------------------------------------------------------------
// GW[b] = WR @ gd[b]: A = gdT[k][m] (reg-staged fp32->fp16), B = WRh[c][m'].
// Writes GWh[b][c][k'] (k perm'd). grid (4 ct, 16 b)
__global__ __launch_bounds__(256) void k_gw(
    const float* __restrict__ gdT, const unsigned short* __restrict__ WRh,
    unsigned short* __restrict__ GWh) {
  const int ct = blockIdx.x, b = blockIdx.y;
  const int tid = threadIdx.x, lane = tid & 63;
  const int w = tid >> 6, wr = w >> 1, wc = w & 1;
  const int kg = lane >> 4, lidx = lane & 15;
  __shared__ unsigned short sG[4096], sWr[4096];
  const float* gb = gdT + (size_t)b * 16384;
  const unsigned short* Wb = WRh + ct * 128 * 128;

  f32x4 acc[4][4];
#pragma unroll
  for (int mf = 0; mf < 4; ++mf)
#pragma unroll
    for (int nf = 0; nf < 4; ++nf) acc[mf][nf] = (f32x4){0.f, 0.f, 0.f, 0.f};

  for (int k0 = 0; k0 < 128; k0 += 32) {
#pragma unroll
    for (int p = 0; p < 2; ++p) {
      int g = tid + p * 256;
      int row = g & 127, kgx = g >> 7;
      const float* s0 = &gb[row * 128 + k0 + 4 * kgx];
      float4 v0 = *(const float4*)s0;
      float4 v1 = *(const float4*)(s0 + 16);
      uint4 u;
      u.x = pk2(v0.x, v0.y); u.y = pk2(v0.z, v0.w);
      u.z = pk2(v1.x, v1.y); u.w = pk2(v1.z, v1.w);
      *(uint4*)&sG[g * 8] = u;
    }
    stage_glds256(sWr, Wb, 128, k0);
    __syncthreads();
    half8 af[4];
#pragma unroll
    for (int mf = 0; mf < 4; ++mf) af[mf] = ld_frag(sG, wr * 64 + mf * 16 + lidx);
#pragma unroll
    for (int nf = 0; nf < 4; ++nf) {
      half8 bf = ld_frag(sWr, wc * 64 + nf * 16 + lidx);
#pragma unroll
      for (int mf = 0; mf < 4; ++mf) acc[mf][nf] = mfma16(af[mf], bf, acc[mf][nf]);
    }
    __syncthreads();
  }
  const size_t gofs = ((size_t)b * 512 + (size_t)ct * 128) * 128;
#pragma unroll
  for (int mf = 0; mf < 4; ++mf) {
    int k0g = wr * 64 + mf * 16 + kg * 4;
    int kp = (k0g & ~31) + perm32(k0g & 31);
#pragma unroll
    for (int nf = 0; nf < 4; ++nf) {
      int c_ = wc * 64 + nf * 16 + lidx;
      ushort4 pk;
      pk.x = f2h(acc[mf][nf][0]); pk.y = f2h(acc[mf][nf][1]);
      pk.z = f2h(acc[mf][nf][2]); pk.w = f2h(acc[mf][nf][3]);
      *(ushort4*)&GWh[gofs + (size_t)c_ * 128 + kp] = pk;
    }
  }
}

// ---------------------------------------------------------------------------
// out[b][c][n] = sum_k GW[b][c][k'] VmT[b][n][k'] + bR[c]; grid (32,4,16)
__global__ __launch_bounds__(256) void k_out(
    const unsigned short* __restrict__ GWh, const unsigned short* __restrict__ VmT,
    const float* __restrict__ bR, float* __restrict__ out) {
  const int nt = blockIdx.x, ct = blockIdx.y, b = blockIdx.z;
  const int tid = threadIdx.x, lane = tid & 63;
  const int w = tid >> 6, wr = w >> 1, wc = w & 1;
  const int kg = lane >> 4, lidx = lane & 15;
  __shared__ unsigned short sW[4096], sZ[4096];
  __shared__ float sBias[128];
  if (tid < 128) sBias[tid] = bR[ct * 128 + tid];
  const unsigned short* Wb = GWh + ((size_t)b * 512 + (size_t)ct * 128) * 128;
  const unsigned short* Zb = VmT + ((size_t)b * 4096 + (size_t)nt * 128) * 128;

  f32x4 acc[4][4];
#pragma unroll
  for (int mf = 0; mf < 4; ++mf)
#pragma unroll
    for (int nf = 0; nf < 4; ++nf) acc[mf][nf] = (f32x4){0.f, 0.f, 0.f, 0.f};

  for (int k0 = 0; k0 < 128; k0 += 32) {
    stage_glds256(sW, Wb, 128, k0);
    stage_glds256(sZ, Zb, 128, k0);
    __syncthreads();
    half8 af[4];
#pragma unroll
    for (int mf = 0; mf < 4; ++mf) af[mf] = ld_frag(sW, wr * 64 + mf * 16 + lidx);
#pragma unroll
    for (int nf = 0; nf < 4; ++nf) {
      half8 bf = ld_frag(sZ, wc * 64 + nf * 16 + lidx);
#pragma unroll
      for (int mf = 0; mf < 4; ++mf) acc[mf][nf] = mfma16(af[mf], bf, acc[mf][nf]);
    }
    __syncthreads();
  }
#pragma unroll
  for (int mf = 0; mf < 4; ++mf)
#pragma unroll
    for (int nf = 0; nf < 4; ++nf)
#pragma unroll
      for (int i = 0; i < 4; ++i) {
        int cl = wr * 64 + mf * 16 + kg * 4 + i;
        int n_ = nt * 128 + wc * 64 + nf * 16 + lidx;
        out[((size_t)b * 512 + ct * 128 + cl) * 4096 + n_] = acc[mf][nf][i] + sBias[cl];
      }
}

// ---------------------------------------------------------------------------
extern "C" void kernel_launch(void* const* d_in, const int* in_sizes, int n_in,
                              void* d_out, int out_size, void* d_ws, size_t ws_size,
                              hipStream_t stream) {
  const float* x  = (const float*)d_in[0];
  const float* WA = (const float*)d_in[1];
  const float* bA = (const float*)d_in[2];
  const float* WB = (const float*)d_in[3];
  const float* bB = (const float*)d_in[4];
  const float* WV = (const float*)d_in[5];
  const float* bV = (const float*)d_in[6];
  const float* WR = (const float*)d_in[7];
  const float* bR = (const float*)d_in[8];
  float* out = (float*)d_out;

  char* ws = (char*)d_ws;
  unsigned short* Wh  = (unsigned short*)(ws);              // 3*128*512 fp16
  unsigned short* WRh = (unsigned short*)(ws + 393216);     // 512*128 fp16
  unsigned short* Ag  = (unsigned short*)(ws + 524288);     // 16 MB tiled A
  unsigned short* Bg  = (unsigned short*)(ws + 17301504);   // 16 MB tiled Bm
  unsigned short* VmT = (unsigned short*)(ws + 34078720);   // 16*4096*128 fp16
  float*          gdP = (float*)(ws + 50855936);            // 16 MB partials
  float*          gdT = (float*)(ws + 67633152);            // 16*128*128 fp32
  unsigned short* GWh = (unsigned short*)(ws + 68681728);   // 16*512*128 fp16

  k_prep<<<1024, 256, 0, stream>>>(WA, WB, WV, WR, Wh, WRh);
  k_gemm_abv<<<1536, 256, 0, stream>>>(x, Wh, bA, bB, bV, Ag, Bg, VmT);
  k_gd<<<dim3(16, 16), 256, 0, stream>>>(Ag, Bg, gdP);
  k_gdred<<<1024, 256, 0, stream>>>(gdP, gdT);
  k_gw<<<dim3(4, 16), 256, 0, stream>>>(gdT, WRh, GWh);
  k_out<<<dim3(32, 4, 16), 256, 0, stream>>>(GWh, VmT, bR, out);
}